// Round 13
// baseline (136.504 us; speedup 1.0000x reference)
//
#include <hip/hip_runtime.h>
#include <math.h>

#define BDIM   4
#define NTOK   4096      // 64*64
#define CDIM   512
#define NHEADS 8
#define HDIM   64
#define NKV    1024      // 32*32 after SR=2
#define HPIX   64
#define WPIX   64

typedef __attribute__((ext_vector_type(8)))  short    short8;
typedef __attribute__((ext_vector_type(4)))  float    floatx4;
typedef __attribute__((ext_vector_type(16))) float    floatx16;
typedef __attribute__((ext_vector_type(4)))  unsigned uintx4;
typedef unsigned short ushort_t;

static __device__ inline unsigned short f2bf(float f) {
  unsigned u = __float_as_uint(f);
  unsigned r = (u + 0x7fffu + ((u >> 16) & 1u)) >> 16;   // RNE
  return (unsigned short)r;
}

// packed f32x2 -> bf16x2
static __device__ inline unsigned cvt_pk_bf16(float lo, float hi) {
  unsigned r;
  asm volatile("v_cvt_pk_bf16_f32 %0, %1, %2" : "=v"(r) : "v"(lo), "v"(hi));
  return r;
}

// v_permlane32_swap_b32: a.upper32lanes <-> b.lower32lanes
static __device__ inline void pl32_swap(unsigned& a, unsigned& b) {
  asm volatile("v_permlane32_swap_b32 %0, %1" : "+v"(a), "+v"(b));
}

// async global->LDS, 16B per lane; LDS dest = wave-uniform base + lane*16
static __device__ inline void gload16(const void* g, void* l) {
  __builtin_amdgcn_global_load_lds(
      (const __attribute__((address_space(1))) void*)g,
      (__attribute__((address_space(3))) void*)l, 16, 0, 0);
}

// ---------------------------------------------------------------------------
// Merged prep: blocks 0..4095 = x f32->bf16; 4096..6143 = weight transposes.
// ---------------------------------------------------------------------------
__global__ __launch_bounds__(256) void prep_kernel(
    const float* __restrict__ x, ushort_t* __restrict__ xb,
    const float* __restrict__ Wq, const float* __restrict__ Wkv,
    const float* __restrict__ Wp, const float* __restrict__ srk,
    ushort_t* __restrict__ Wqt, ushort_t* __restrict__ Wkvt,
    ushort_t* __restrict__ Wpt, ushort_t* __restrict__ srkt) {
  const int bid = blockIdx.x;
  if (bid < 4096) {
    const size_t i = ((size_t)bid * 256 + threadIdx.x) * 8;
    float4 f0 = *(const float4*)&x[i];
    float4 f1 = *(const float4*)&x[i + 4];
    short8 v;
    v[0] = (short)f2bf(f0.x); v[1] = (short)f2bf(f0.y);
    v[2] = (short)f2bf(f0.z); v[3] = (short)f2bf(f0.w);
    v[4] = (short)f2bf(f1.x); v[5] = (short)f2bf(f1.y);
    v[6] = (short)f2bf(f1.z); v[7] = (short)f2bf(f1.w);
    *(short8*)&xb[i] = v;
    return;
  }
  __shared__ float t[32][33];
  const int tb = bid - 4096;
  const float* in; ushort_t* outp; int C, tile;
  if (tb < 256)       { in = Wq;  outp = Wqt;  C = 512;  tile = tb; }
  else if (tb < 768)  { in = Wkv; outp = Wkvt; C = 1024; tile = tb - 256; }
  else if (tb < 1024) { in = Wp;  outp = Wpt;  C = 512;  tile = tb - 768; }
  else                { in = srk; outp = srkt; C = 512;  tile = tb - 1024; }
  const int R = (tb >= 1024) ? 2048 : 512;
  const int tcn = C >> 5;
  const int r0 = (tile / tcn) * 32, c0 = (tile % tcn) * 32;
  const int tr = threadIdx.x & 31, tc = threadIdx.x >> 5;
#pragma unroll
  for (int i = 0; i < 4; ++i)
    t[tc + 8 * i][tr] = in[(size_t)(r0 + tc + 8 * i) * C + c0 + tr];
  __syncthreads();
#pragma unroll
  for (int i = 0; i < 4; ++i)
    outp[(size_t)(c0 + tc + 8 * i) * R + r0 + tr] = f2bf(t[tr][tc + 8 * i]);
}

// ---------------------------------------------------------------------------
// bf16 MFMA GEMM (generic, used for out-proj): C = (A @ Bt^T + bias) * scale
// ---------------------------------------------------------------------------
__global__ __launch_bounds__(256) void gemm_bf16(
    const ushort_t* __restrict__ A, const ushort_t* __restrict__ Bt,
    const float* __restrict__ bias, float* __restrict__ Cf,
    ushort_t* __restrict__ Cb, int M, int N, int K, float scale) {
  __shared__ char As[16384];
  __shared__ char Bs[16384];
  const int tid = threadIdx.x;
  const int w = tid >> 6, lane = tid & 63;
  const int g = lane >> 4, qr = lane & 15;
  const int wr = w >> 1, wc = w & 1;
  const int row0 = blockIdx.x * 128, col0 = blockIdx.y * 128;
  const int rl = w * 8 + (lane >> 3);
  const int sch = (lane & 7) ^ ((lane >> 3) & 7);

  floatx4 acc[4][4] = {};

  for (int k0 = 0; k0 < K; k0 += 64) {
    __syncthreads();
#pragma unroll
    for (int i = 0; i < 4; ++i) {
      const int r = rl + 32 * i;
      const unsigned lb = (unsigned)(w * 1024 + i * 4096);
      gload16(&A[(size_t)(row0 + r) * K + k0 + sch * 8], As + lb);
      gload16(&Bt[(size_t)(col0 + r) * K + k0 + sch * 8], Bs + lb);
    }
    __syncthreads();

#pragma unroll
    for (int kc = 0; kc < 2; ++kc) {
      short8 af[4], bfr[4];
#pragma unroll
      for (int mi = 0; mi < 4; ++mi) {
        const int r = wr * 64 + mi * 16 + qr;
        af[mi] = *(const short8*)(As +
            ((unsigned)(r * 128 + kc * 64 + g * 16) ^ (unsigned)((r & 7) << 4)));
      }
#pragma unroll
      for (int ni = 0; ni < 4; ++ni) {
        const int c = wc * 64 + ni * 16 + qr;
        bfr[ni] = *(const short8*)(Bs +
            ((unsigned)(c * 128 + kc * 64 + g * 16) ^ (unsigned)((c & 7) << 4)));
      }
#pragma unroll
      for (int mi = 0; mi < 4; ++mi)
#pragma unroll
        for (int ni = 0; ni < 4; ++ni)
          acc[mi][ni] = __builtin_amdgcn_mfma_f32_16x16x32_bf16(
              af[mi], bfr[ni], acc[mi][ni], 0, 0, 0);
    }
  }

#pragma unroll
  for (int mi = 0; mi < 4; ++mi) {
#pragma unroll
    for (int ni = 0; ni < 4; ++ni) {
      const int col = col0 + wc * 64 + ni * 16 + qr;
      const float bv = bias[col];
#pragma unroll
      for (int ri = 0; ri < 4; ++ri) {
        const int row = row0 + wr * 64 + mi * 16 + g * 4 + ri;
        const float v = (acc[mi][ni][ri] + bv) * scale;
        if (Cb) Cb[(size_t)row * N + col] = f2bf(v);
        else    Cf[(size_t)row * N + col] = v;
      }
    }
  }
}

// ---------------------------------------------------------------------------
// Merged conv + Q-GEMM launch. Blocks 0..255: implicit-im2col conv
// (128x64 tile, K=2048). Blocks 256..767: Q = (x@Wq+bq)*qscale.
// ---------------------------------------------------------------------------
__global__ __launch_bounds__(256) void qconv_gemm(
    const ushort_t* __restrict__ xb, const ushort_t* __restrict__ srkt,
    const float* __restrict__ srb, float* __restrict__ XR,
    const ushort_t* __restrict__ Wqt, const float* __restrict__ bq,
    ushort_t* __restrict__ Qb, float qscale) {
  __shared__ char As[16384];
  __shared__ char Bs[16384];
  const int tid = threadIdx.x;
  const int w = tid >> 6, lane = tid & 63;
  const int g = lane >> 4, qr = lane & 15;
  const int wr = w >> 1, wc = w & 1;
  const int rl = w * 8 + (lane >> 3);
  const int sch = (lane & 7) ^ ((lane >> 3) & 7);

  if (blockIdx.x < 256) {
    // ---- conv path ----
    const int cb = blockIdx.x;
    const int row0 = (cb & 31) * 128, col0 = (cb >> 5) * 64;
    floatx4 acc[4][2] = {};

    for (int k0 = 0; k0 < 2048; k0 += 64) {
      __syncthreads();
      {
        const int di = k0 >> 10, dj = (k0 >> 9) & 1, cib = (k0 & 511) + sch * 8;
#pragma unroll
        for (int i = 0; i < 4; ++i) {
          const int r = rl + 32 * i;
          const int gr = row0 + r;
          const int bb = gr >> 10, p = gr & 1023;
          const int oi = p >> 5, oj = p & 31;
          const size_t off =
              ((size_t)((bb * HPIX + 2 * oi + di) * WPIX + 2 * oj + dj)) * CDIM + cib;
          gload16(&xb[off], As + (unsigned)(w * 1024 + i * 4096));
        }
#pragma unroll
        for (int i = 0; i < 2; ++i) {
          const int r = rl + 32 * i;
          gload16(&srkt[(size_t)(col0 + r) * 2048 + k0 + sch * 8],
                  Bs + (unsigned)(w * 1024 + i * 4096));
        }
      }
      __syncthreads();

#pragma unroll
      for (int kc = 0; kc < 2; ++kc) {
        short8 af[4], bfr[2];
#pragma unroll
        for (int mi = 0; mi < 4; ++mi) {
          const int r = wr * 64 + mi * 16 + qr;
          af[mi] = *(const short8*)(As +
              ((unsigned)(r * 128 + kc * 64 + g * 16) ^ (unsigned)((r & 7) << 4)));
        }
#pragma unroll
        for (int ni = 0; ni < 2; ++ni) {
          const int c = wc * 32 + ni * 16 + qr;
          bfr[ni] = *(const short8*)(Bs +
              ((unsigned)(c * 128 + kc * 64 + g * 16) ^ (unsigned)((c & 7) << 4)));
        }
#pragma unroll
        for (int mi = 0; mi < 4; ++mi)
#pragma unroll
          for (int ni = 0; ni < 2; ++ni)
            acc[mi][ni] = __builtin_amdgcn_mfma_f32_16x16x32_bf16(
                af[mi], bfr[ni], acc[mi][ni], 0, 0, 0);
      }
    }

#pragma unroll
    for (int mi = 0; mi < 4; ++mi) {
#pragma unroll
      for (int ni = 0; ni < 2; ++ni) {
        const int col = col0 + wc * 32 + ni * 16 + qr;
        const float bv = srb[col];
#pragma unroll
        for (int ri = 0; ri < 4; ++ri) {
          const int row = row0 + wr * 64 + mi * 16 + g * 4 + ri;
          XR[(size_t)row * 512 + col] = acc[mi][ni][ri] + bv;
        }
      }
    }
  } else {
    // ---- Q-GEMM path ----
    const int qb = blockIdx.x - 256;
    const int row0 = (qb & 127) * 128, col0 = (qb >> 7) * 128;
    floatx4 acc[4][4] = {};

    for (int k0 = 0; k0 < 512; k0 += 64) {
      __syncthreads();
#pragma unroll
      for (int i = 0; i < 4; ++i) {
        const int r = rl + 32 * i;
        const unsigned lb = (unsigned)(w * 1024 + i * 4096);
        gload16(&xb[(size_t)(row0 + r) * 512 + k0 + sch * 8], As + lb);
        gload16(&Wqt[(size_t)(col0 + r) * 512 + k0 + sch * 8], Bs + lb);
      }
      __syncthreads();

#pragma unroll
      for (int kc = 0; kc < 2; ++kc) {
        short8 af[4], bfr[4];
#pragma unroll
        for (int mi = 0; mi < 4; ++mi) {
          const int r = wr * 64 + mi * 16 + qr;
          af[mi] = *(const short8*)(As +
              ((unsigned)(r * 128 + kc * 64 + g * 16) ^ (unsigned)((r & 7) << 4)));
        }
#pragma unroll
        for (int ni = 0; ni < 4; ++ni) {
          const int c = wc * 64 + ni * 16 + qr;
          bfr[ni] = *(const short8*)(Bs +
              ((unsigned)(c * 128 + kc * 64 + g * 16) ^ (unsigned)((c & 7) << 4)));
        }
#pragma unroll
        for (int mi = 0; mi < 4; ++mi)
#pragma unroll
          for (int ni = 0; ni < 4; ++ni)
            acc[mi][ni] = __builtin_amdgcn_mfma_f32_16x16x32_bf16(
                af[mi], bfr[ni], acc[mi][ni], 0, 0, 0);
      }
    }

#pragma unroll
    for (int mi = 0; mi < 4; ++mi) {
#pragma unroll
      for (int ni = 0; ni < 4; ++ni) {
        const int col = col0 + wc * 64 + ni * 16 + qr;
        const float bv = bq[col];
#pragma unroll
        for (int ri = 0; ri < 4; ++ri) {
          const int row = row0 + wr * 64 + mi * 16 + g * 4 + ri;
          Qb[(size_t)row * 512 + col] = f2bf((acc[mi][ni][ri] + bv) * qscale);
        }
      }
    }
  }
}

// ---------------------------------------------------------------------------
// KV GEMM with FRAGMENT-ORDER image epilogue. Per (b,h,t) 8KB tile:
//  K: byte = (st*4+ks)*1024 + (hi*32+ql)*16 + j*2  = K[st*32+ql][ks*16+hi*8+j]
//  V: byte = (st*4+db*2+hf16)*1024 + (hi*32+ql)*16 + c*4 + odd*2
//     = V[st*32+hf16*16+hi*8+2c+odd][db*32+ql]
// ---------------------------------------------------------------------------
__global__ __launch_bounds__(256) void gemm_kv(
    const ushort_t* __restrict__ A, const ushort_t* __restrict__ Bt,
    const float* __restrict__ bias, char* __restrict__ Kimg,
    char* __restrict__ Vimg) {
  __shared__ char As[16384];
  __shared__ char Bs[16384];
  const int tid = threadIdx.x;
  const int w = tid >> 6, lane = tid & 63;
  const int g = lane >> 4, qr = lane & 15;
  const int wr = w >> 1, wc = w & 1;
  const int row0 = blockIdx.x * 128, col0 = blockIdx.y * 128;
  const int rl = w * 8 + (lane >> 3);
  const int sch = (lane & 7) ^ ((lane >> 3) & 7);

  floatx4 acc[4][4] = {};

  for (int k0 = 0; k0 < 512; k0 += 64) {
    __syncthreads();
#pragma unroll
    for (int i = 0; i < 4; ++i) {
      const int r = rl + 32 * i;
      const unsigned lb = (unsigned)(w * 1024 + i * 4096);
      gload16(&A[(size_t)(row0 + r) * 512 + k0 + sch * 8], As + lb);
      gload16(&Bt[(size_t)(col0 + r) * 512 + k0 + sch * 8], Bs + lb);
    }
    __syncthreads();

#pragma unroll
    for (int kc = 0; kc < 2; ++kc) {
      short8 af[4], bfr[4];
#pragma unroll
      for (int mi = 0; mi < 4; ++mi) {
        const int r = wr * 64 + mi * 16 + qr;
        af[mi] = *(const short8*)(As +
            ((unsigned)(r * 128 + kc * 64 + g * 16) ^ (unsigned)((r & 7) << 4)));
      }
#pragma unroll
      for (int ni = 0; ni < 4; ++ni) {
        const int c = wc * 64 + ni * 16 + qr;
        bfr[ni] = *(const short8*)(Bs +
            ((unsigned)(c * 128 + kc * 64 + g * 16) ^ (unsigned)((c & 7) << 4)));
      }
#pragma unroll
      for (int mi = 0; mi < 4; ++mi)
#pragma unroll
        for (int ni = 0; ni < 4; ++ni)
          acc[mi][ni] = __builtin_amdgcn_mfma_f32_16x16x32_bf16(
              af[mi], bfr[ni], acc[mi][ni], 0, 0, 0);
    }
  }

#pragma unroll
  for (int mi = 0; mi < 4; ++mi) {
#pragma unroll
    for (int ni = 0; ni < 4; ++ni) {
      const int col = col0 + wc * 64 + ni * 16 + qr;
      const float bv = bias[col];
#pragma unroll
      for (int ri = 0; ri < 4; ++ri) {
        const int row = row0 + wr * 64 + mi * 16 + g * 4 + ri;
        const ushort_t v = f2bf(acc[mi][ni][ri] + bv);
        const int b = row >> 10, m = row & 1023;
        const int t = m >> 6, mr = m & 63;
        const int st = mr >> 5;
        if (col < 512) {
          const int h = col >> 6, d = col & 63;
          const int ql = mr & 31;
          const int ks = d >> 4, hi2 = (d >> 3) & 1, j = d & 7;
          char* img = Kimg + (((size_t)(b * NHEADS + h) * 16 + t) << 13);
          *(ushort_t*)(img + (unsigned)(((st * 4 + ks) << 10) +
                       ((hi2 << 5) + ql) * 16 + j * 2)) = v;
        } else {
          const int c = col - 512, h = c >> 6, d = c & 63;
          const int r5 = mr & 31;
          const int hf16 = r5 >> 4, rem = r5 & 15;
          const int hi2 = rem >> 3, cc = (rem >> 1) & 3, odd = rem & 1;
          const int db = d >> 5, ql = d & 31;
          char* img = Vimg + (((size_t)(b * NHEADS + h) * 16 + t) << 13);
          *(ushort_t*)(img + (unsigned)(((st * 4 + db * 2 + hf16) << 10) +
                       ((hi2 << 5) + ql) * 16 + cc * 4 + odd * 2)) = v;
        }
      }
    }
  }
}

// ---------------------------------------------------------------------------
// LayerNorm (512, eps 1e-3): f32 in -> bf16 out
// ---------------------------------------------------------------------------
__global__ __launch_bounds__(256) void ln_kernel(
    const float* __restrict__ in, ushort_t* __restrict__ out,
    const float* __restrict__ gamma, const float* __restrict__ beta) {
  const int row = blockIdx.x * 4 + (threadIdx.x >> 6);
  const int lane = threadIdx.x & 63;
  const float* p = in + (size_t)row * CDIM;
  float v[8];
  float s = 0.f;
#pragma unroll
  for (int j = 0; j < 8; ++j) { v[j] = p[lane + j * 64]; s += v[j]; }
#pragma unroll
  for (int o = 32; o > 0; o >>= 1) s += __shfl_xor(s, o);
  const float mu = s * (1.0f / 512.0f);
  float vs = 0.f;
#pragma unroll
  for (int j = 0; j < 8; ++j) { const float d = v[j] - mu; vs += d * d; }
#pragma unroll
  for (int o = 32; o > 0; o >>= 1) vs += __shfl_xor(vs, o);
  const float rstd = rsqrtf(vs * (1.0f / 512.0f) + 1e-3f);
  ushort_t* q = out + (size_t)row * CDIM;
#pragma unroll
  for (int j = 0; j < 8; ++j) {
    const int c = lane + j * 64;
    q[c] = f2bf((v[j] - mu) * rstd * gamma[c] + beta[c]);
  }
}

// ---------------------------------------------------------------------------
// Fused flash attention: swapped-QK^T 32x32, fragment-linear LDS (0 conflict),
// r9/r12 single-buffer staging (proven), 256 q-rows per block: each wave
// owns TWO 32-q groups (halves) sharing the staged K/V tiles — every kf/v
// LDS read feeds 2 MFMAs, staging+barrier cost amortized 2x, KV image
// traffic halved. l via MFMA vs all-ones B (Lacc[half][r] in Oacc's row map).
// ---------------------------------------------------------------------------
__global__ __launch_bounds__(256) void attn_kernel(
    const ushort_t* __restrict__ Q, const char* __restrict__ Kimg,
    const char* __restrict__ Vimg, ushort_t* __restrict__ AO) {
  __shared__ char Ks[16384];       // 2 tiles x 8 slabs x 1024B, fragment order
  __shared__ char Vt[16384];

  const int b = blockIdx.z, h = blockIdx.y;
  const int q0 = blockIdx.x * 256;
  const int tid = threadIdx.x;
  const int w = tid >> 6, lane = tid & 63;
  const int ql = lane & 31;
  const int hi = lane >> 5;
  const unsigned lbyte = (unsigned)(lane * 16);

  short8 qf[2][4];
#pragma unroll
  for (int half = 0; half < 2; ++half) {
    const ushort_t* qp =
        &Q[((size_t)(b * NTOK + q0 + 64 * w + 32 * half + ql)) * CDIM + h * HDIM];
#pragma unroll
    for (int ks = 0; ks < 4; ++ks)
      qf[half][ks] = *(const short8*)&qp[ks * 16 + hi * 8];
  }

  short8 ones;
#pragma unroll
  for (int i = 0; i < 8; ++i) ones[i] = (short)0x3F80;   // bf16 1.0

  const char* kbase = Kimg + (((size_t)(b * NHEADS + h)) << 17);  // 16 tiles * 8KB
  const char* vbase = Vimg + (((size_t)(b * NHEADS + h)) << 17);

  floatx16 Oacc[2][2] = {};        // [half][db]
  floatx16 Lacc[2] = {};

  for (int t2 = 0; t2 < NKV / 128; ++t2) {
    __syncthreads();
    {
      const char* kg = kbase + ((size_t)t2 << 14) + w * 4096 + lane * 16;
      const char* vg = vbase + ((size_t)t2 << 14) + w * 4096 + lane * 16;
      char* kd = Ks + w * 4096;
      char* vd = Vt + w * 4096;
#pragma unroll
      for (int i = 0; i < 4; ++i) {
        gload16(kg + i * 1024, kd + i * 1024);
        gload16(vg + i * 1024, vd + i * 1024);
      }
    }
    __syncthreads();

#pragma unroll
    for (int sub = 0; sub < 2; ++sub) {
      const char* ksb = Ks + sub * 8192 + lbyte;
      const char* vtb = Vt + sub * 8192 + lbyte;

#pragma unroll
      for (int st = 0; st < 2; ++st) {
        // ---- QK^T both halves: each kf read feeds 2 MFMAs ----
        floatx16 s0 = {}, s1 = {};
        __builtin_amdgcn_s_setprio(1);
#pragma unroll
        for (int ks = 0; ks < 4; ++ks) {
          short8 kf = *(const short8*)(ksb + ((st * 4 + ks) << 10));
          s0 = __builtin_amdgcn_mfma_f32_32x32x16_bf16(kf, qf[0][ks], s0, 0, 0, 0);
          s1 = __builtin_amdgcn_mfma_f32_32x32x16_bf16(kf, qf[1][ks], s1, 0, 0, 0);
        }
        __builtin_amdgcn_s_setprio(0);

        // ---- P = exp2(S'), pack PV A-fragments per half ----
        short8 pa0[2], pa1[2];
#pragma unroll
        for (int half = 0; half < 2; ++half) {
          const floatx16 sv = half ? s1 : s0;
          unsigned W[8];
#pragma unroll
          for (int i = 0; i < 8; ++i) {
            const float pa = __builtin_amdgcn_exp2f(sv[2 * i]);
            const float pb = __builtin_amdgcn_exp2f(sv[2 * i + 1]);
            W[i] = cvt_pk_bf16(pa, pb);
          }
          pl32_swap(W[0], W[2]); pl32_swap(W[1], W[3]);
          pl32_swap(W[4], W[6]); pl32_swap(W[5], W[7]);
          uintx4 u0 = {W[0], W[1], W[2], W[3]};
          uintx4 u1 = {W[4], W[5], W[6], W[7]};
          pa0[half] = __builtin_bit_cast(short8, u0);
          pa1[half] = __builtin_bit_cast(short8, u1);
        }

        // ---- PV: v reads shared across halves; + l via ones-MFMA ----
        __builtin_amdgcn_s_setprio(1);
#pragma unroll
        for (int db = 0; db < 2; ++db) {
          short8 v0 = *(const short8*)(vtb + ((st * 4 + db * 2) << 10));
          short8 v1 = *(const short8*)(vtb + ((st * 4 + db * 2 + 1) << 10));
#pragma unroll
          for (int half = 0; half < 2; ++half) {
            Oacc[half][db] = __builtin_amdgcn_mfma_f32_32x32x16_bf16(
                pa0[half], v0, Oacc[half][db], 0, 0, 0);
            Oacc[half][db] = __builtin_amdgcn_mfma_f32_32x32x16_bf16(
                pa1[half], v1, Oacc[half][db], 0, 0, 0);
          }
        }
#pragma unroll
        for (int half = 0; half < 2; ++half) {
          Lacc[half] = __builtin_amdgcn_mfma_f32_32x32x16_bf16(
              pa0[half], ones, Lacc[half], 0, 0, 0);
          Lacc[half] = __builtin_amdgcn_mfma_f32_32x32x16_bf16(
              pa1[half], ones, Lacc[half], 0, 0, 0);
        }
        __builtin_amdgcn_s_setprio(0);
      }
    }
  }

  // ---- epilogue: Lacc[half][r] shares Oacc's exact row mapping ----
#pragma unroll
  for (int half = 0; half < 2; ++half) {
#pragma unroll
    for (int r = 0; r < 16; ++r) {
      const int qrow = (r & 3) + 8 * (r >> 2) + 4 * hi;
      const float iv = 1.0f / Lacc[half][r];
      const size_t rowoff =
          ((size_t)(b * NTOK + q0 + 64 * w + 32 * half + qrow)) * CDIM + h * HDIM;
      AO[rowoff + ql]      = f2bf(Oacc[half][0][r] * iv);
      AO[rowoff + 32 + ql] = f2bf(Oacc[half][1][r] * iv);
    }
  }
}

// ---------------------------------------------------------------------------
extern "C" void kernel_launch(void* const* d_in, const int* in_sizes, int n_in,
                              void* d_out, int out_size, void* d_ws, size_t ws_size,
                              hipStream_t stream) {
  const float* x     = (const float*)d_in[0];
  const float* Wq    = (const float*)d_in[3];
  const float* bq    = (const float*)d_in[4];
  const float* Wkv   = (const float*)d_in[5];
  const float* bkv   = (const float*)d_in[6];
  const float* Wp    = (const float*)d_in[7];
  const float* bp    = (const float*)d_in[8];
  const float* srk   = (const float*)d_in[9];   // [2,2,512,512] == [2048,512]
  const float* srb   = (const float*)d_in[10];
  const float* gamma = (const float*)d_in[11];
  const float* beta  = (const float*)d_in[12];
  float* out = (float*)d_out;

  // workspace layout
  ushort_t* xb   = (ushort_t*)d_ws;                 // [16384,512]
  ushort_t* Qb   = xb + (size_t)16384 * 512;        // [16384,512]
  ushort_t* AOb  = Qb + (size_t)16384 * 512;        // [16384,512]
  float*    XR   = (float*)(AOb + (size_t)16384 * 512); // conv out f32 [4096,512]
  ushort_t* XL   = (ushort_t*)(XR + (size_t)4096 * 512);// LN out [4096,512]
  char*     Kimg = (char*)(XL + (size_t)4096 * 512);    // 4MB
  char*     Vimg = Kimg + (size_t)4 * 8 * 16 * 8192;    // 4MB
  ushort_t* Wqt  = (ushort_t*)(Vimg + (size_t)4 * 8 * 16 * 8192);  // [512,512]
  ushort_t* Wkvt = Wqt + (size_t)512 * 512;         // [1024,512]
  ushort_t* Wpt  = Wkvt + (size_t)1024 * 512;       // [512,512]
  ushort_t* srkt = Wpt + (size_t)512 * 512;         // [512,2048]

  prep_kernel<<<4096 + 2048, 256, 0, stream>>>(
      x, xb, Wq, Wkv, Wp, srk, Wqt, Wkvt, Wpt, srkt);

  // conv (blocks 0..255) + Q-GEMM (blocks 256..767) in one launch
  qconv_gemm<<<768, 256, 0, stream>>>(
      xb, srkt, srb, XR, Wqt, bq, Qb, 0.125f * 1.44269504f);
  // LN -> bf16
  ln_kernel<<<4096 / 4, 256, 0, stream>>>(XR, XL, gamma, beta);
  // KV projection -> fragment-order K/V images
  gemm_kv<<<dim3(4096 / 128, 1024 / 128), 256, 0, stream>>>(
      XL, Wkvt, bkv, Kimg, Vimg);
  // attention -> AO bf16 (256 q-rows per block)
  attn_kernel<<<dim3(NTOK / 256, NHEADS, BDIM), 256, 0, stream>>>(Qb, Kimg, Vimg, AOb);
  // out = AO @ Wp + bp -> f32
  gemm_bf16<<<dim3(16384 / 128, 512 / 128), 256, 0, stream>>>(
      AOb, Wpt, bp, out, nullptr, 16384, 512, 512, 1.0f);
}

// Round 14
// 125.867 us; speedup vs baseline: 1.0845x; 1.0845x over previous
//
#include <hip/hip_runtime.h>
#include <math.h>

#define BDIM   4
#define NTOK   4096      // 64*64
#define CDIM   512
#define NHEADS 8
#define HDIM   64
#define NKV    1024      // 32*32 after SR=2
#define HPIX   64
#define WPIX   64

typedef __attribute__((ext_vector_type(8)))  short    short8;
typedef __attribute__((ext_vector_type(4)))  float    floatx4;
typedef __attribute__((ext_vector_type(16))) float    floatx16;
typedef __attribute__((ext_vector_type(4)))  unsigned uintx4;
typedef unsigned short ushort_t;

static __device__ inline unsigned short f2bf(float f) {
  unsigned u = __float_as_uint(f);
  unsigned r = (u + 0x7fffu + ((u >> 16) & 1u)) >> 16;   // RNE
  return (unsigned short)r;
}

// packed f32x2 -> bf16x2
static __device__ inline unsigned cvt_pk_bf16(float lo, float hi) {
  unsigned r;
  asm volatile("v_cvt_pk_bf16_f32 %0, %1, %2" : "=v"(r) : "v"(lo), "v"(hi));
  return r;
}

// v_permlane32_swap_b32: a.upper32lanes <-> b.lower32lanes
static __device__ inline void pl32_swap(unsigned& a, unsigned& b) {
  asm volatile("v_permlane32_swap_b32 %0, %1" : "+v"(a), "+v"(b));
}

// async global->LDS, 16B per lane; LDS dest = wave-uniform base + lane*16
static __device__ inline void gload16(const void* g, void* l) {
  __builtin_amdgcn_global_load_lds(
      (const __attribute__((address_space(1))) void*)g,
      (__attribute__((address_space(3))) void*)l, 16, 0, 0);
}

// ---------------------------------------------------------------------------
// Merged prep: blocks 0..4095 = x f32->bf16; 4096..6143 = weight transposes.
// ---------------------------------------------------------------------------
__global__ __launch_bounds__(256) void prep_kernel(
    const float* __restrict__ x, ushort_t* __restrict__ xb,
    const float* __restrict__ Wq, const float* __restrict__ Wkv,
    const float* __restrict__ Wp, const float* __restrict__ srk,
    ushort_t* __restrict__ Wqt, ushort_t* __restrict__ Wkvt,
    ushort_t* __restrict__ Wpt, ushort_t* __restrict__ srkt) {
  const int bid = blockIdx.x;
  if (bid < 4096) {
    const size_t i = ((size_t)bid * 256 + threadIdx.x) * 8;
    float4 f0 = *(const float4*)&x[i];
    float4 f1 = *(const float4*)&x[i + 4];
    short8 v;
    v[0] = (short)f2bf(f0.x); v[1] = (short)f2bf(f0.y);
    v[2] = (short)f2bf(f0.z); v[3] = (short)f2bf(f0.w);
    v[4] = (short)f2bf(f1.x); v[5] = (short)f2bf(f1.y);
    v[6] = (short)f2bf(f1.z); v[7] = (short)f2bf(f1.w);
    *(short8*)&xb[i] = v;
    return;
  }
  __shared__ float t[32][33];
  const int tb = bid - 4096;
  const float* in; ushort_t* outp; int C, tile;
  if (tb < 256)       { in = Wq;  outp = Wqt;  C = 512;  tile = tb; }
  else if (tb < 768)  { in = Wkv; outp = Wkvt; C = 1024; tile = tb - 256; }
  else if (tb < 1024) { in = Wp;  outp = Wpt;  C = 512;  tile = tb - 768; }
  else                { in = srk; outp = srkt; C = 512;  tile = tb - 1024; }
  const int R = (tb >= 1024) ? 2048 : 512;
  const int tcn = C >> 5;
  const int r0 = (tile / tcn) * 32, c0 = (tile % tcn) * 32;
  const int tr = threadIdx.x & 31, tc = threadIdx.x >> 5;
#pragma unroll
  for (int i = 0; i < 4; ++i)
    t[tc + 8 * i][tr] = in[(size_t)(r0 + tc + 8 * i) * C + c0 + tr];
  __syncthreads();
#pragma unroll
  for (int i = 0; i < 4; ++i)
    outp[(size_t)(c0 + tc + 8 * i) * R + r0 + tr] = f2bf(t[tr][tc + 8 * i]);
}

// ---------------------------------------------------------------------------
// bf16 MFMA GEMM (generic, used for out-proj): C = (A @ Bt^T + bias) * scale
// ---------------------------------------------------------------------------
__global__ __launch_bounds__(256) void gemm_bf16(
    const ushort_t* __restrict__ A, const ushort_t* __restrict__ Bt,
    const float* __restrict__ bias, float* __restrict__ Cf,
    ushort_t* __restrict__ Cb, int M, int N, int K, float scale) {
  __shared__ char As[16384];
  __shared__ char Bs[16384];
  const int tid = threadIdx.x;
  const int w = tid >> 6, lane = tid & 63;
  const int g = lane >> 4, qr = lane & 15;
  const int wr = w >> 1, wc = w & 1;
  const int row0 = blockIdx.x * 128, col0 = blockIdx.y * 128;
  const int rl = w * 8 + (lane >> 3);
  const int sch = (lane & 7) ^ ((lane >> 3) & 7);

  floatx4 acc[4][4] = {};

  for (int k0 = 0; k0 < K; k0 += 64) {
    __syncthreads();
#pragma unroll
    for (int i = 0; i < 4; ++i) {
      const int r = rl + 32 * i;
      const unsigned lb = (unsigned)(w * 1024 + i * 4096);
      gload16(&A[(size_t)(row0 + r) * K + k0 + sch * 8], As + lb);
      gload16(&Bt[(size_t)(col0 + r) * K + k0 + sch * 8], Bs + lb);
    }
    __syncthreads();

#pragma unroll
    for (int kc = 0; kc < 2; ++kc) {
      short8 af[4], bfr[4];
#pragma unroll
      for (int mi = 0; mi < 4; ++mi) {
        const int r = wr * 64 + mi * 16 + qr;
        af[mi] = *(const short8*)(As +
            ((unsigned)(r * 128 + kc * 64 + g * 16) ^ (unsigned)((r & 7) << 4)));
      }
#pragma unroll
      for (int ni = 0; ni < 4; ++ni) {
        const int c = wc * 64 + ni * 16 + qr;
        bfr[ni] = *(const short8*)(Bs +
            ((unsigned)(c * 128 + kc * 64 + g * 16) ^ (unsigned)((c & 7) << 4)));
      }
#pragma unroll
      for (int mi = 0; mi < 4; ++mi)
#pragma unroll
        for (int ni = 0; ni < 4; ++ni)
          acc[mi][ni] = __builtin_amdgcn_mfma_f32_16x16x32_bf16(
              af[mi], bfr[ni], acc[mi][ni], 0, 0, 0);
    }
  }

#pragma unroll
  for (int mi = 0; mi < 4; ++mi) {
#pragma unroll
    for (int ni = 0; ni < 4; ++ni) {
      const int col = col0 + wc * 64 + ni * 16 + qr;
      const float bv = bias[col];
#pragma unroll
      for (int ri = 0; ri < 4; ++ri) {
        const int row = row0 + wr * 64 + mi * 16 + g * 4 + ri;
        const float v = (acc[mi][ni][ri] + bv) * scale;
        if (Cb) Cb[(size_t)row * N + col] = f2bf(v);
        else    Cf[(size_t)row * N + col] = v;
      }
    }
  }
}

// ---------------------------------------------------------------------------
// Merged conv + Q-GEMM launch. Blocks 0..255: implicit-im2col conv
// (128x64 tile, K=2048). Blocks 256..767: Q = (x@Wq+bq)*qscale.
// ---------------------------------------------------------------------------
__global__ __launch_bounds__(256) void qconv_gemm(
    const ushort_t* __restrict__ xb, const ushort_t* __restrict__ srkt,
    const float* __restrict__ srb, float* __restrict__ XR,
    const ushort_t* __restrict__ Wqt, const float* __restrict__ bq,
    ushort_t* __restrict__ Qb, float qscale) {
  __shared__ char As[16384];
  __shared__ char Bs[16384];
  const int tid = threadIdx.x;
  const int w = tid >> 6, lane = tid & 63;
  const int g = lane >> 4, qr = lane & 15;
  const int wr = w >> 1, wc = w & 1;
  const int rl = w * 8 + (lane >> 3);
  const int sch = (lane & 7) ^ ((lane >> 3) & 7);

  if (blockIdx.x < 256) {
    // ---- conv path ----
    const int cb = blockIdx.x;
    const int row0 = (cb & 31) * 128, col0 = (cb >> 5) * 64;
    floatx4 acc[4][2] = {};

    for (int k0 = 0; k0 < 2048; k0 += 64) {
      __syncthreads();
      {
        const int di = k0 >> 10, dj = (k0 >> 9) & 1, cib = (k0 & 511) + sch * 8;
#pragma unroll
        for (int i = 0; i < 4; ++i) {
          const int r = rl + 32 * i;
          const int gr = row0 + r;
          const int bb = gr >> 10, p = gr & 1023;
          const int oi = p >> 5, oj = p & 31;
          const size_t off =
              ((size_t)((bb * HPIX + 2 * oi + di) * WPIX + 2 * oj + dj)) * CDIM + cib;
          gload16(&xb[off], As + (unsigned)(w * 1024 + i * 4096));
        }
#pragma unroll
        for (int i = 0; i < 2; ++i) {
          const int r = rl + 32 * i;
          gload16(&srkt[(size_t)(col0 + r) * 2048 + k0 + sch * 8],
                  Bs + (unsigned)(w * 1024 + i * 4096));
        }
      }
      __syncthreads();

#pragma unroll
      for (int kc = 0; kc < 2; ++kc) {
        short8 af[4], bfr[2];
#pragma unroll
        for (int mi = 0; mi < 4; ++mi) {
          const int r = wr * 64 + mi * 16 + qr;
          af[mi] = *(const short8*)(As +
              ((unsigned)(r * 128 + kc * 64 + g * 16) ^ (unsigned)((r & 7) << 4)));
        }
#pragma unroll
        for (int ni = 0; ni < 2; ++ni) {
          const int c = wc * 32 + ni * 16 + qr;
          bfr[ni] = *(const short8*)(Bs +
              ((unsigned)(c * 128 + kc * 64 + g * 16) ^ (unsigned)((c & 7) << 4)));
        }
#pragma unroll
        for (int mi = 0; mi < 4; ++mi)
#pragma unroll
          for (int ni = 0; ni < 2; ++ni)
            acc[mi][ni] = __builtin_amdgcn_mfma_f32_16x16x32_bf16(
                af[mi], bfr[ni], acc[mi][ni], 0, 0, 0);
      }
    }

#pragma unroll
    for (int mi = 0; mi < 4; ++mi) {
#pragma unroll
      for (int ni = 0; ni < 2; ++ni) {
        const int col = col0 + wc * 32 + ni * 16 + qr;
        const float bv = srb[col];
#pragma unroll
        for (int ri = 0; ri < 4; ++ri) {
          const int row = row0 + wr * 64 + mi * 16 + g * 4 + ri;
          XR[(size_t)row * 512 + col] = acc[mi][ni][ri] + bv;
        }
      }
    }
  } else {
    // ---- Q-GEMM path ----
    const int qb = blockIdx.x - 256;
    const int row0 = (qb & 127) * 128, col0 = (qb >> 7) * 128;
    floatx4 acc[4][4] = {};

    for (int k0 = 0; k0 < 512; k0 += 64) {
      __syncthreads();
#pragma unroll
      for (int i = 0; i < 4; ++i) {
        const int r = rl + 32 * i;
        const unsigned lb = (unsigned)(w * 1024 + i * 4096);
        gload16(&xb[(size_t)(row0 + r) * 512 + k0 + sch * 8], As + lb);
        gload16(&Wqt[(size_t)(col0 + r) * 512 + k0 + sch * 8], Bs + lb);
      }
      __syncthreads();

#pragma unroll
      for (int kc = 0; kc < 2; ++kc) {
        short8 af[4], bfr[4];
#pragma unroll
        for (int mi = 0; mi < 4; ++mi) {
          const int r = wr * 64 + mi * 16 + qr;
          af[mi] = *(const short8*)(As +
              ((unsigned)(r * 128 + kc * 64 + g * 16) ^ (unsigned)((r & 7) << 4)));
        }
#pragma unroll
        for (int ni = 0; ni < 4; ++ni) {
          const int c = wc * 64 + ni * 16 + qr;
          bfr[ni] = *(const short8*)(Bs +
              ((unsigned)(c * 128 + kc * 64 + g * 16) ^ (unsigned)((c & 7) << 4)));
        }
#pragma unroll
        for (int mi = 0; mi < 4; ++mi)
#pragma unroll
          for (int ni = 0; ni < 4; ++ni)
            acc[mi][ni] = __builtin_amdgcn_mfma_f32_16x16x32_bf16(
                af[mi], bfr[ni], acc[mi][ni], 0, 0, 0);
      }
    }

#pragma unroll
    for (int mi = 0; mi < 4; ++mi) {
#pragma unroll
      for (int ni = 0; ni < 4; ++ni) {
        const int col = col0 + wc * 64 + ni * 16 + qr;
        const float bv = bq[col];
#pragma unroll
        for (int ri = 0; ri < 4; ++ri) {
          const int row = row0 + wr * 64 + mi * 16 + g * 4 + ri;
          Qb[(size_t)row * 512 + col] = f2bf((acc[mi][ni][ri] + bv) * qscale);
        }
      }
    }
  }
}

// ---------------------------------------------------------------------------
// KV GEMM with FRAGMENT-ORDER image epilogue. Per (b,h,t) 8KB tile:
//  K: byte = (st*4+ks)*1024 + (hi*32+ql)*16 + j*2  = K[st*32+ql][ks*16+hi*8+j]
//  V: byte = (st*4+db*2+hf16)*1024 + (hi*32+ql)*16 + c*4 + odd*2
//     = V[st*32+hf16*16+hi*8+2c+odd][db*32+ql]
// ---------------------------------------------------------------------------
__global__ __launch_bounds__(256) void gemm_kv(
    const ushort_t* __restrict__ A, const ushort_t* __restrict__ Bt,
    const float* __restrict__ bias, char* __restrict__ Kimg,
    char* __restrict__ Vimg) {
  __shared__ char As[16384];
  __shared__ char Bs[16384];
  const int tid = threadIdx.x;
  const int w = tid >> 6, lane = tid & 63;
  const int g = lane >> 4, qr = lane & 15;
  const int wr = w >> 1, wc = w & 1;
  const int row0 = blockIdx.x * 128, col0 = blockIdx.y * 128;
  const int rl = w * 8 + (lane >> 3);
  const int sch = (lane & 7) ^ ((lane >> 3) & 7);

  floatx4 acc[4][4] = {};

  for (int k0 = 0; k0 < 512; k0 += 64) {
    __syncthreads();
#pragma unroll
    for (int i = 0; i < 4; ++i) {
      const int r = rl + 32 * i;
      const unsigned lb = (unsigned)(w * 1024 + i * 4096);
      gload16(&A[(size_t)(row0 + r) * 512 + k0 + sch * 8], As + lb);
      gload16(&Bt[(size_t)(col0 + r) * 512 + k0 + sch * 8], Bs + lb);
    }
    __syncthreads();

#pragma unroll
    for (int kc = 0; kc < 2; ++kc) {
      short8 af[4], bfr[4];
#pragma unroll
      for (int mi = 0; mi < 4; ++mi) {
        const int r = wr * 64 + mi * 16 + qr;
        af[mi] = *(const short8*)(As +
            ((unsigned)(r * 128 + kc * 64 + g * 16) ^ (unsigned)((r & 7) << 4)));
      }
#pragma unroll
      for (int ni = 0; ni < 4; ++ni) {
        const int c = wc * 64 + ni * 16 + qr;
        bfr[ni] = *(const short8*)(Bs +
            ((unsigned)(c * 128 + kc * 64 + g * 16) ^ (unsigned)((c & 7) << 4)));
      }
#pragma unroll
      for (int mi = 0; mi < 4; ++mi)
#pragma unroll
        for (int ni = 0; ni < 4; ++ni)
          acc[mi][ni] = __builtin_amdgcn_mfma_f32_16x16x32_bf16(
              af[mi], bfr[ni], acc[mi][ni], 0, 0, 0);
    }
  }

#pragma unroll
  for (int mi = 0; mi < 4; ++mi) {
#pragma unroll
    for (int ni = 0; ni < 4; ++ni) {
      const int col = col0 + wc * 64 + ni * 16 + qr;
      const float bv = bias[col];
#pragma unroll
      for (int ri = 0; ri < 4; ++ri) {
        const int row = row0 + wr * 64 + mi * 16 + g * 4 + ri;
        const ushort_t v = f2bf(acc[mi][ni][ri] + bv);
        const int b = row >> 10, m = row & 1023;
        const int t = m >> 6, mr = m & 63;
        const int st = mr >> 5;
        if (col < 512) {
          const int h = col >> 6, d = col & 63;
          const int ql = mr & 31;
          const int ks = d >> 4, hi2 = (d >> 3) & 1, j = d & 7;
          char* img = Kimg + (((size_t)(b * NHEADS + h) * 16 + t) << 13);
          *(ushort_t*)(img + (unsigned)(((st * 4 + ks) << 10) +
                       ((hi2 << 5) + ql) * 16 + j * 2)) = v;
        } else {
          const int c = col - 512, h = c >> 6, d = c & 63;
          const int r5 = mr & 31;
          const int hf16 = r5 >> 4, rem = r5 & 15;
          const int hi2 = rem >> 3, cc = (rem >> 1) & 3, odd = rem & 1;
          const int db = d >> 5, ql = d & 31;
          char* img = Vimg + (((size_t)(b * NHEADS + h) * 16 + t) << 13);
          *(ushort_t*)(img + (unsigned)(((st * 4 + db * 2 + hf16) << 10) +
                       ((hi2 << 5) + ql) * 16 + cc * 4 + odd * 2)) = v;
        }
      }
    }
  }
}

// ---------------------------------------------------------------------------
// LayerNorm (512, eps 1e-3): f32 in -> bf16 out
// ---------------------------------------------------------------------------
__global__ __launch_bounds__(256) void ln_kernel(
    const float* __restrict__ in, ushort_t* __restrict__ out,
    const float* __restrict__ gamma, const float* __restrict__ beta) {
  const int row = blockIdx.x * 4 + (threadIdx.x >> 6);
  const int lane = threadIdx.x & 63;
  const float* p = in + (size_t)row * CDIM;
  float v[8];
  float s = 0.f;
#pragma unroll
  for (int j = 0; j < 8; ++j) { v[j] = p[lane + j * 64]; s += v[j]; }
#pragma unroll
  for (int o = 32; o > 0; o >>= 1) s += __shfl_xor(s, o);
  const float mu = s * (1.0f / 512.0f);
  float vs = 0.f;
#pragma unroll
  for (int j = 0; j < 8; ++j) { const float d = v[j] - mu; vs += d * d; }
#pragma unroll
  for (int o = 32; o > 0; o >>= 1) vs += __shfl_xor(vs, o);
  const float rstd = rsqrtf(vs * (1.0f / 512.0f) + 1e-3f);
  ushort_t* q = out + (size_t)row * CDIM;
#pragma unroll
  for (int j = 0; j < 8; ++j) {
    const int c = lane + j * 64;
    q[c] = f2bf((v[j] - mu) * rstd * gamma[c] + beta[c]);
  }
}

// ---------------------------------------------------------------------------
// Fused flash attention (r12 structure, proven): swapped-QK^T 32x32,
// fragment-linear LDS (0 conflicts), single-buffer 2-tile staging,
// no-max softmax, l via ones-MFMA. NEW: 1D grid with id%8 == head so all
// blocks sharing a (b,h) KV image land on one XCD (L2 locality, T1) —
// bijective decode h=id&7, b=(id>>3)&3, qx=id>>5.
// ---------------------------------------------------------------------------
__global__ __launch_bounds__(256) void attn_kernel(
    const ushort_t* __restrict__ Q, const char* __restrict__ Kimg,
    const char* __restrict__ Vimg, ushort_t* __restrict__ AO) {
  __shared__ char Ks[16384];       // 2 tiles x 8 slabs x 1024B, fragment order
  __shared__ char Vt[16384];

  const int id = blockIdx.x;
  const int h = id & 7;
  const int b = (id >> 3) & 3;
  const int q0 = (id >> 5) * 128;
  const int tid = threadIdx.x;
  const int w = tid >> 6, lane = tid & 63;
  const int ql = lane & 31;
  const int hi = lane >> 5;
  const unsigned lbyte = (unsigned)(lane * 16);

  short8 qf[4];
  {
    const ushort_t* qp = &Q[((size_t)(b * NTOK + q0 + 32 * w + ql)) * CDIM + h * HDIM];
#pragma unroll
    for (int ks = 0; ks < 4; ++ks)
      qf[ks] = *(const short8*)&qp[ks * 16 + hi * 8];
  }

  short8 ones;
#pragma unroll
  for (int i = 0; i < 8; ++i) ones[i] = (short)0x3F80;   // bf16 1.0

  const char* kbase = Kimg + (((size_t)(b * NHEADS + h)) << 17);  // 16 tiles * 8KB
  const char* vbase = Vimg + (((size_t)(b * NHEADS + h)) << 17);

  floatx16 Oacc[2] = {};
  floatx16 Lacc = {};

  for (int t2 = 0; t2 < NKV / 128; ++t2) {
    __syncthreads();
    {
      const char* kg = kbase + ((size_t)t2 << 14) + w * 4096 + lane * 16;
      const char* vg = vbase + ((size_t)t2 << 14) + w * 4096 + lane * 16;
      char* kd = Ks + w * 4096;
      char* vd = Vt + w * 4096;
#pragma unroll
      for (int i = 0; i < 4; ++i) {
        gload16(kg + i * 1024, kd + i * 1024);
        gload16(vg + i * 1024, vd + i * 1024);
      }
    }
    __syncthreads();

#pragma unroll
    for (int sub = 0; sub < 2; ++sub) {
      const char* ksb = Ks + sub * 8192 + lbyte;
      const char* vtb = Vt + sub * 8192 + lbyte;

      // ---- QK^T swapped: base + imm reads (conflict-free) ----
      floatx16 sacc[2];
      __builtin_amdgcn_s_setprio(1);
#pragma unroll
      for (int st = 0; st < 2; ++st) {
        floatx16 s_ = {};
#pragma unroll
        for (int ks = 0; ks < 4; ++ks) {
          short8 kf = *(const short8*)(ksb + ((st * 4 + ks) << 10));
          s_ = __builtin_amdgcn_mfma_f32_32x32x16_bf16(kf, qf[ks], s_, 0, 0, 0);
        }
        sacc[st] = s_;
      }
      __builtin_amdgcn_s_setprio(0);

      // ---- P = exp2(S'), pack PV A-fragments, PV + l via ones-MFMA ----
#pragma unroll
      for (int st = 0; st < 2; ++st) {
        unsigned W[8];
#pragma unroll
        for (int i = 0; i < 8; ++i) {
          const float pa = __builtin_amdgcn_exp2f(sacc[st][2 * i]);
          const float pb = __builtin_amdgcn_exp2f(sacc[st][2 * i + 1]);
          W[i] = cvt_pk_bf16(pa, pb);
        }
        pl32_swap(W[0], W[2]); pl32_swap(W[1], W[3]);
        pl32_swap(W[4], W[6]); pl32_swap(W[5], W[7]);
        uintx4 u0 = {W[0], W[1], W[2], W[3]};
        uintx4 u1 = {W[4], W[5], W[6], W[7]};
        const short8 pa0 = __builtin_bit_cast(short8, u0);
        const short8 pa1 = __builtin_bit_cast(short8, u1);
        __builtin_amdgcn_s_setprio(1);
#pragma unroll
        for (int db = 0; db < 2; ++db) {
          short8 v0 = *(const short8*)(vtb + ((st * 4 + db * 2) << 10));
          short8 v1 = *(const short8*)(vtb + ((st * 4 + db * 2 + 1) << 10));
          Oacc[db] = __builtin_amdgcn_mfma_f32_32x32x16_bf16(pa0, v0, Oacc[db], 0, 0, 0);
          Oacc[db] = __builtin_amdgcn_mfma_f32_32x32x16_bf16(pa1, v1, Oacc[db], 0, 0, 0);
        }
        Lacc = __builtin_amdgcn_mfma_f32_32x32x16_bf16(pa0, ones, Lacc, 0, 0, 0);
        Lacc = __builtin_amdgcn_mfma_f32_32x32x16_bf16(pa1, ones, Lacc, 0, 0, 0);
        __builtin_amdgcn_s_setprio(0);
      }
    }
  }

  // ---- epilogue: Lacc[r] is the row-sum in Oacc's exact row mapping ----
#pragma unroll
  for (int r = 0; r < 16; ++r) {
    const int qrow = (r & 3) + 8 * (r >> 2) + 4 * hi;
    const float iv = 1.0f / Lacc[r];
    const size_t rowoff =
        ((size_t)(b * NTOK + q0 + 32 * w + qrow)) * CDIM + h * HDIM;
    AO[rowoff + ql]      = f2bf(Oacc[0][r] * iv);
    AO[rowoff + 32 + ql] = f2bf(Oacc[1][r] * iv);
  }
}

// ---------------------------------------------------------------------------
extern "C" void kernel_launch(void* const* d_in, const int* in_sizes, int n_in,
                              void* d_out, int out_size, void* d_ws, size_t ws_size,
                              hipStream_t stream) {
  const float* x     = (const float*)d_in[0];
  const float* Wq    = (const float*)d_in[3];
  const float* bq    = (const float*)d_in[4];
  const float* Wkv   = (const float*)d_in[5];
  const float* bkv   = (const float*)d_in[6];
  const float* Wp    = (const float*)d_in[7];
  const float* bp    = (const float*)d_in[8];
  const float* srk   = (const float*)d_in[9];   // [2,2,512,512] == [2048,512]
  const float* srb   = (const float*)d_in[10];
  const float* gamma = (const float*)d_in[11];
  const float* beta  = (const float*)d_in[12];
  float* out = (float*)d_out;

  // workspace layout
  ushort_t* xb   = (ushort_t*)d_ws;                 // [16384,512]
  ushort_t* Qb   = xb + (size_t)16384 * 512;        // [16384,512]
  ushort_t* AOb  = Qb + (size_t)16384 * 512;        // [16384,512]
  float*    XR   = (float*)(AOb + (size_t)16384 * 512); // conv out f32 [4096,512]
  ushort_t* XL   = (ushort_t*)(XR + (size_t)4096 * 512);// LN out [4096,512]
  char*     Kimg = (char*)(XL + (size_t)4096 * 512);    // 4MB
  char*     Vimg = Kimg + (size_t)4 * 8 * 16 * 8192;    // 4MB
  ushort_t* Wqt  = (ushort_t*)(Vimg + (size_t)4 * 8 * 16 * 8192);  // [512,512]
  ushort_t* Wkvt = Wqt + (size_t)512 * 512;         // [1024,512]
  ushort_t* Wpt  = Wkvt + (size_t)1024 * 512;       // [512,512]
  ushort_t* srkt = Wpt + (size_t)512 * 512;         // [512,2048]

  prep_kernel<<<4096 + 2048, 256, 0, stream>>>(
      x, xb, Wq, Wkv, Wp, srk, Wqt, Wkvt, Wpt, srkt);

  // conv (blocks 0..255) + Q-GEMM (blocks 256..767) in one launch
  qconv_gemm<<<768, 256, 0, stream>>>(
      xb, srkt, srb, XR, Wqt, bq, Qb, 0.125f * 1.44269504f);
  // LN -> bf16
  ln_kernel<<<4096 / 4, 256, 0, stream>>>(XR, XL, gamma, beta);
  // KV projection -> fragment-order K/V images
  gemm_kv<<<dim3(4096 / 128, 1024 / 128), 256, 0, stream>>>(
      XL, Wkvt, bkv, Kimg, Vimg);
  // attention -> AO bf16 (1D grid, id%8==head for XCD/L2 locality)
  attn_kernel<<<(NTOK / 128) * NHEADS * BDIM, 256, 0, stream>>>(Qb, Kimg, Vimg, AOb);
  // out = AO @ Wp + bp -> f32
  gemm_bf16<<<dim3(16384 / 128, 512 / 128), 256, 0, stream>>>(
      AOb, Wpt, bp, out, nullptr, 16384, 512, 512, 1.0f);
}